// Round 5
// baseline (46.207 us; speedup 1.0000x reference)
//
#include <hip/hip_runtime.h>
#include <hip/hip_bf16.h>
#include <math.h>

#define DEMBED 512
#define NTOK   (64 * 1024)
#define TPB    256
#define BLOCKS 2048
#define WAVES  (BLOCKS * TPB / 64)     // 8192 waves
#define TPW    (NTOK / WAVES)          // 8 tokens per wave

typedef float f4 __attribute__((ext_vector_type(4)));

// Streaming store: non-temporal + system-scope (write-through, no L2/MALL
// allocation) so the 134 MB output stream does not evict the 64 MiB table.
__device__ __forceinline__ void store_stream(f4* addr, f4 v) {
    asm volatile("global_store_dwordx4 %0, %1, off nt sc1"
                 :: "v"(addr), "v"(v) : "memory");
}

// One wave owns one token row (2 KB) per iteration: lane covers 16 B at
// byte offsets lane*16 and lane*16+1024. Index loads are scalarized via
// readfirstlane so the scalar unit runs ahead of the vector gather.
__global__ void __launch_bounds__(TPB)
embed_kernel(const int* __restrict__ x,
             const float* __restrict__ table,
             float* __restrict__ out)
{
    const int lane = threadIdx.x & 63;
    int wave = (blockIdx.x * TPB + threadIdx.x) >> 6;
    wave = __builtin_amdgcn_readfirstlane(wave);   // SGPR wave id
    const int tok0 = wave * TPW;

    // ---- positional values for this lane's two float4 slots ----
    f4 pA, pB;
    const float kLog = logf(10000.0f) / (float)DEMBED;
#pragma unroll
    for (int j = 0; j < 4; ++j) {
        int   ia  = lane * 4 + j;
        float ea  = expf(-(float)(ia & ~1) * kLog);
        float aa  = (float)ia * ea;
        pA[j] = (ia & 1) ? cosf(aa) : sinf(aa);
        int   ib  = 256 + lane * 4 + j;
        float eb  = expf(-(float)(ib & ~1) * kLog);
        float ab  = (float)ib * eb;
        pB[j] = (ib & 1) ? cosf(ab) : sinf(ab);
    }

    // ---- scalar index loads, issued up front ----
    int rows[TPW];
#pragma unroll
    for (int i = 0; i < TPW; ++i)
        rows[i] = x[tok0 + i];                     // uniform addr -> s_load

    // ---- 16 independent table loads in flight ----
#pragma unroll
    for (int i = 0; i < TPW; ++i) {
        const f4* __restrict__ src = (const f4*)(table + (size_t)rows[i] * DEMBED);
        f4 a = src[lane];                          // first 1 KB of row
        f4 b = src[lane + 64];                     // second 1 KB
        f4 ra = a + pA;
        f4 rb = b + pB;
        f4* __restrict__ dst = (f4*)(out + (size_t)(tok0 + i) * DEMBED);
        store_stream(&dst[lane], ra);
        store_stream(&dst[lane + 64], rb);
    }
}

extern "C" void kernel_launch(void* const* d_in, const int* in_sizes, int n_in,
                              void* d_out, int out_size, void* d_ws, size_t ws_size,
                              hipStream_t stream) {
    const int*   x     = (const int*)d_in[0];      // [64,1024] token ids
    const float* table = (const float*)d_in[1];    // [32000,512]
    float*       out   = (float*)d_out;            // [64,1024,512]

    embed_kernel<<<BLOCKS, TPB, 0, stream>>>(x, table, out);
}

// Round 6
// 45.365 us; speedup vs baseline: 1.0186x; 1.0186x over previous
//
#include <hip/hip_runtime.h>
#include <hip/hip_bf16.h>
#include <math.h>

#define DEMBED 512
#define NTOK   (64 * 1024)
#define TPB    256
#define BLOCKS 1024
#define WAVES  (BLOCKS * TPB / 64)     // 4096 waves
#define TPW    (NTOK / WAVES)          // 16 tokens per wave

typedef float f4 __attribute__((ext_vector_type(4)));

// One wave owns one token row (2 KB) per iteration: lane covers 16 B at
// byte offsets lane*16 and lane*16+1024. Index loads are scalarized via
// readfirstlane so the scalar unit runs ahead of the vector gather.
__global__ void __launch_bounds__(TPB)
embed_kernel(const int* __restrict__ x,
             const float* __restrict__ table,
             float* __restrict__ out)
{
    const int lane = threadIdx.x & 63;
    int wave = (blockIdx.x * TPB + threadIdx.x) >> 6;
    wave = __builtin_amdgcn_readfirstlane(wave);   // SGPR wave id
    const int tok0 = wave * TPW;

    // ---- positional values for this lane's two float4 slots ----
    f4 pA, pB;
    const float kLog = logf(10000.0f) / (float)DEMBED;
#pragma unroll
    for (int j = 0; j < 4; ++j) {
        int   ia  = lane * 4 + j;
        float ea  = expf(-(float)(ia & ~1) * kLog);
        float aa  = (float)ia * ea;
        pA[j] = (ia & 1) ? cosf(aa) : sinf(aa);
        int   ib  = 256 + lane * 4 + j;
        float eb  = expf(-(float)(ib & ~1) * kLog);
        float ab  = (float)ib * eb;
        pB[j] = (ib & 1) ? cosf(ab) : sinf(ab);
    }

    // ---- scalar index loads, issued up front ----
    int rows[TPW];
#pragma unroll
    for (int i = 0; i < TPW; ++i)
        rows[i] = x[tok0 + i];                     // uniform addr -> s_load

    // ---- 32 independent table loads in flight ----
#pragma unroll
    for (int i = 0; i < TPW; ++i) {
        const f4* __restrict__ src = (const f4*)(table + (size_t)rows[i] * DEMBED);
        f4 a = src[lane];                          // first 1 KB of row
        f4 b = src[lane + 64];                     // second 1 KB
        f4 ra = a + pA;
        f4 rb = b + pB;
        f4* __restrict__ dst = (f4*)(out + (size_t)(tok0 + i) * DEMBED);
        dst[lane]      = ra;                       // plain stores (A/B vs nt)
        dst[lane + 64] = rb;
    }
}

extern "C" void kernel_launch(void* const* d_in, const int* in_sizes, int n_in,
                              void* d_out, int out_size, void* d_ws, size_t ws_size,
                              hipStream_t stream) {
    const int*   x     = (const int*)d_in[0];      // [64,1024] token ids
    const float* table = (const float*)d_in[1];    // [32000,512]
    float*       out   = (float*)d_out;            // [64,1024,512]

    embed_kernel<<<BLOCKS, TPB, 0, stream>>>(x, table, out);
}

// Round 7
// 44.255 us; speedup vs baseline: 1.0441x; 1.0251x over previous
//
#include <hip/hip_runtime.h>
#include <hip/hip_bf16.h>
#include <math.h>

#define DEMBED 512
#define NTOK   (64 * 1024)
#define TPB    256
#define BLOCKS 2048
#define WAVES  (BLOCKS * TPB / 64)     // 8192 waves
#define TPW    (NTOK / WAVES)          // 8 tokens per wave

typedef float f4 __attribute__((ext_vector_type(4)));

// One wave owns one token row (2 KB) per iteration: lane covers 16 B at
// byte offsets lane*16 and lane*16+1024. Index loads are scalarized via
// readfirstlane so the scalar unit runs ahead of the vector gather.
// Best-measured config (R4): nt stores, TPW=8, 2048 blocks -> 44.2 us
// = 96.5% of the 268 MB zero-reuse mixed-stream roofline at 6.29 TB/s.
__global__ void __launch_bounds__(TPB)
embed_kernel(const int* __restrict__ x,
             const float* __restrict__ table,
             float* __restrict__ out)
{
    const int lane = threadIdx.x & 63;
    int wave = (blockIdx.x * TPB + threadIdx.x) >> 6;
    wave = __builtin_amdgcn_readfirstlane(wave);   // SGPR wave id
    const int tok0 = wave * TPW;

    // ---- positional values for this lane's two float4 slots ----
    f4 pA, pB;
    const float kLog = logf(10000.0f) / (float)DEMBED;
#pragma unroll
    for (int j = 0; j < 4; ++j) {
        int   ia  = lane * 4 + j;
        float ea  = expf(-(float)(ia & ~1) * kLog);
        float aa  = (float)ia * ea;
        pA[j] = (ia & 1) ? cosf(aa) : sinf(aa);
        int   ib  = 256 + lane * 4 + j;
        float eb  = expf(-(float)(ib & ~1) * kLog);
        float ab  = (float)ib * eb;
        pB[j] = (ib & 1) ? cosf(ab) : sinf(ab);
    }

    // ---- scalar index loads, issued up front ----
    int rows[TPW];
#pragma unroll
    for (int i = 0; i < TPW; ++i)
        rows[i] = x[tok0 + i];                     // uniform addr -> s_load

    // ---- 16 independent table loads in flight ----
#pragma unroll
    for (int i = 0; i < TPW; ++i) {
        const f4* __restrict__ src = (const f4*)(table + (size_t)rows[i] * DEMBED);
        f4 a = src[lane];                          // first 1 KB of row
        f4 b = src[lane + 64];                     // second 1 KB
        f4 ra = a + pA;
        f4 rb = b + pB;
        f4* __restrict__ dst = (f4*)(out + (size_t)(tok0 + i) * DEMBED);
        __builtin_nontemporal_store(ra, &dst[lane]);
        __builtin_nontemporal_store(rb, &dst[lane + 64]);
    }
}

extern "C" void kernel_launch(void* const* d_in, const int* in_sizes, int n_in,
                              void* d_out, int out_size, void* d_ws, size_t ws_size,
                              hipStream_t stream) {
    const int*   x     = (const int*)d_in[0];      // [64,1024] token ids
    const float* table = (const float*)d_in[1];    // [32000,512]
    float*       out   = (float*)d_out;            // [64,1024,512]

    embed_kernel<<<BLOCKS, TPB, 0, stream>>>(x, table, out);
}